// Round 1
// baseline (87.456 us; speedup 1.0000x reference)
//
#include <hip/hip_runtime.h>
#include <hip/hip_bf16.h>

// Quantum circuit: 4 qubits, batch 131072.
// angles[b][q] = sum_{g<16} x[b][g*4+q]  (RY fusion, as in reference)
// psi = kron_q [cos(a_q/2), sin(a_q/2)]   (REAL product state)
// out[b][q] = psi^T M_q psi, where M_q = Re(U^dag Z_q U), U = fixed 2-layer unitary(params).
// Setup kernel builds M (4KB) in d_ws; main kernel evaluates the quadratic forms.

__global__ void qc_setup(const float* __restrict__ params, float* __restrict__ M)
{
    // one block, 256 threads. Threads 0..15 each simulate one basis column of U.
    __shared__ float Ur[16][16];  // [k][col]
    __shared__ float Ui[16][16];
    const int tid = threadIdx.x;

    if (tid < 16) {
        const int col = tid;
        float ur[16], ui[16];
        #pragma unroll
        for (int k = 0; k < 16; ++k) { ur[k] = (k == col) ? 1.f : 0.f; ui[k] = 0.f; }

        #pragma unroll
        for (int l = 0; l < 2; ++l) {
            // --- Rot(phi, theta, omega) on each qubit ---
            #pragma unroll
            for (int q = 0; q < 4; ++q) {
                const float phi = params[l*12 + q*3 + 0];
                const float th  = params[l*12 + q*3 + 1];
                const float om  = params[l*12 + q*3 + 2];
                const float ct = cosf(0.5f*th), st = sinf(0.5f*th);
                const float ap = 0.5f*(phi + om), am = 0.5f*(phi - om);
                const float cap = cosf(ap), sap = sinf(ap);
                const float cam = cosf(am), sam = sinf(am);
                // U00 = ct e^{-i ap}; U01 = -st e^{+i am}; U10 = st e^{-i am}; U11 = ct e^{+i ap}
                const float u00r =  ct*cap, u00i = -ct*sap;
                const float u01r = -st*cam, u01i = -st*sam;
                const float u10r =  st*cam, u10i = -st*sam;
                const float u11r =  ct*cap, u11i =  ct*sap;
                const int bit = 1 << (3 - q);
                #pragma unroll
                for (int k = 0; k < 16; ++k) {
                    if (k & bit) continue;
                    const int k1 = k | bit;
                    const float arr = ur[k],  aii = ui[k];
                    const float brr = ur[k1], bii = ui[k1];
                    ur[k]  = u00r*arr - u00i*aii + u01r*brr - u01i*bii;
                    ui[k]  = u00r*aii + u00i*arr + u01r*bii + u01i*brr;
                    ur[k1] = u10r*arr - u10i*aii + u11r*brr - u11i*bii;
                    ui[k1] = u10r*aii + u10i*arr + u11r*bii + u11i*brr;
                }
            }
            // --- CNOT ring: (0,1),(1,2),(2,3),(3,0) ---
            const int cs[4] = {0,1,2,3}, ts[4] = {1,2,3,0};
            #pragma unroll
            for (int e = 0; e < 4; ++e) {
                const int cb = 3 - cs[e], tb = 3 - ts[e];
                float nr[16], ni[16];
                #pragma unroll
                for (int k = 0; k < 16; ++k) {
                    const int src = ((k >> cb) & 1) ? (k ^ (1 << tb)) : k;
                    nr[k] = ur[src]; ni[k] = ui[src];
                }
                #pragma unroll
                for (int k = 0; k < 16; ++k) { ur[k] = nr[k]; ui[k] = ni[k]; }
            }
        }
        #pragma unroll
        for (int k = 0; k < 16; ++k) { Ur[k][col] = ur[k]; Ui[k][col] = ui[k]; }
    }
    __syncthreads();

    // Each of the 256 threads computes one (i,j) entry, all 4 observables.
    // M_q[i][j] = sum_k z_q(k) * (Ur[k][i]Ur[k][j] + Ui[k][i]Ui[k][j])
    // Off-diagonals doubled (main kernel only walks j >= i).
    const int i = tid >> 4, j = tid & 15;
    float m0 = 0.f, m1 = 0.f, m2 = 0.f, m3 = 0.f;
    #pragma unroll
    for (int k = 0; k < 16; ++k) {
        const float dot = Ur[k][i]*Ur[k][j] + Ui[k][i]*Ui[k][j];
        m0 += ((k >> 3) & 1) ? -dot : dot;
        m1 += ((k >> 2) & 1) ? -dot : dot;
        m2 += ((k >> 1) & 1) ? -dot : dot;
        m3 += ( k       & 1) ? -dot : dot;
    }
    const float sc = (i == j) ? 1.f : 2.f;
    float4 o; o.x = m0*sc; o.y = m1*sc; o.z = m2*sc; o.w = m3*sc;
    reinterpret_cast<float4*>(M)[i*16 + j] = o;
}

__global__ __launch_bounds__(256) void qc_main(const float4* __restrict__ x4,
                                               const float4* __restrict__ Mg,
                                               float4* __restrict__ out4)
{
    __shared__ float4 Mlds[256];
    const int tid = threadIdx.x;
    Mlds[tid] = Mg[tid];   // coalesced 4KB stage
    __syncthreads();

    const int b = blockIdx.x * 256 + tid;
    const float4* row = x4 + ((size_t)b << 4);

    // angle sums (x row is 64 floats = 16 float4; lanes of float4 = qubits)
    float a0 = 0.f, a1 = 0.f, a2 = 0.f, a3 = 0.f;
    #pragma unroll
    for (int j = 0; j < 16; ++j) {
        const float4 v = row[j];
        a0 += v.x; a1 += v.y; a2 += v.z; a3 += v.w;
    }

    float c0,s0,c1,s1,c2,s2,c3,s3;
    sincosf(0.5f*a0, &s0, &c0);
    sincosf(0.5f*a1, &s1, &c1);
    sincosf(0.5f*a2, &s2, &c2);
    sincosf(0.5f*a3, &s3, &c3);

    // psi[k], k = b0*8 + b1*4 + b2*2 + b3
    float p23[4] = { c2*c3, c2*s3, s2*c3, s2*s3 };
    float p123[8];
    #pragma unroll
    for (int t = 0; t < 4; ++t) { p123[t] = c1*p23[t]; p123[4+t] = s1*p23[t]; }
    float psi[16];
    #pragma unroll
    for (int u = 0; u < 8; ++u) { psi[u] = c0*p123[u]; psi[8+u] = s0*p123[u]; }

    // quadratic forms, upper triangle (off-diag pre-doubled in M)
    float ax = 0.f, ay = 0.f, az = 0.f, aw = 0.f;
    #pragma unroll
    for (int i = 0; i < 16; ++i) {
        #pragma unroll
        for (int j = i; j < 16; ++j) {
            const float pp = psi[i] * psi[j];
            const float4 m = Mlds[i*16 + j];   // uniform addr -> LDS broadcast
            ax = fmaf(pp, m.x, ax);
            ay = fmaf(pp, m.y, ay);
            az = fmaf(pp, m.z, az);
            aw = fmaf(pp, m.w, aw);
        }
    }
    float4 r; r.x = ax; r.y = ay; r.z = az; r.w = aw;
    out4[b] = r;
}

extern "C" void kernel_launch(void* const* d_in, const int* in_sizes, int n_in,
                              void* d_out, int out_size, void* d_ws, size_t ws_size,
                              hipStream_t stream)
{
    const float* x      = (const float*)d_in[0];
    const float* params = (const float*)d_in[1];
    float*       out    = (float*)d_out;
    float*       M      = (float*)d_ws;   // 1024 floats = 4KB

    qc_setup<<<1, 256, 0, stream>>>(params, M);

    const int batch = in_sizes[0] / 64;            // 131072
    qc_main<<<batch / 256, 256, 0, stream>>>(
        (const float4*)x, (const float4*)M, (float4*)out);
}

// Round 2
// 84.156 us; speedup vs baseline: 1.0392x; 1.0392x over previous
//
#include <hip/hip_runtime.h>
#include <hip/hip_bf16.h>

// Quantum circuit: 4 qubits, batch 131072.
// angles[b][q] = sum_{g<16} x[b][g*4+q]  (RY fusion, as in reference)
// psi = kron_q [cos(a_q/2), sin(a_q/2)]   (REAL product state)
// out[b][q] = psi^T M_q psi, where M_q = Re(U^dag Z_q U), U = fixed 2-layer unitary(params).
// Setup kernel builds M (4KB) in d_ws; main kernel evaluates the quadratic forms.
// M is wave-uniform -> read via scalar loads (s_load_dwordx4), no LDS at all.

__global__ void qc_setup(const float* __restrict__ params, float* __restrict__ M)
{
    // one block, 256 threads. Threads 0..15 each simulate one basis column of U.
    __shared__ float Ur[16][16];  // [k][col]
    __shared__ float Ui[16][16];
    const int tid = threadIdx.x;

    if (tid < 16) {
        const int col = tid;
        float ur[16], ui[16];
        #pragma unroll
        for (int k = 0; k < 16; ++k) { ur[k] = (k == col) ? 1.f : 0.f; ui[k] = 0.f; }

        #pragma unroll
        for (int l = 0; l < 2; ++l) {
            // --- Rot(phi, theta, omega) on each qubit ---
            #pragma unroll
            for (int q = 0; q < 4; ++q) {
                const float phi = params[l*12 + q*3 + 0];
                const float th  = params[l*12 + q*3 + 1];
                const float om  = params[l*12 + q*3 + 2];
                const float ct = cosf(0.5f*th), st = sinf(0.5f*th);
                const float ap = 0.5f*(phi + om), am = 0.5f*(phi - om);
                const float cap = cosf(ap), sap = sinf(ap);
                const float cam = cosf(am), sam = sinf(am);
                // U00 = ct e^{-i ap}; U01 = -st e^{+i am}; U10 = st e^{-i am}; U11 = ct e^{+i ap}
                const float u00r =  ct*cap, u00i = -ct*sap;
                const float u01r = -st*cam, u01i = -st*sam;
                const float u10r =  st*cam, u10i = -st*sam;
                const float u11r =  ct*cap, u11i =  ct*sap;
                const int bit = 1 << (3 - q);
                #pragma unroll
                for (int k = 0; k < 16; ++k) {
                    if (k & bit) continue;
                    const int k1 = k | bit;
                    const float arr = ur[k],  aii = ui[k];
                    const float brr = ur[k1], bii = ui[k1];
                    ur[k]  = u00r*arr - u00i*aii + u01r*brr - u01i*bii;
                    ui[k]  = u00r*aii + u00i*arr + u01r*bii + u01i*brr;
                    ur[k1] = u10r*arr - u10i*aii + u11r*brr - u11i*bii;
                    ui[k1] = u10r*aii + u10i*arr + u11r*bii + u11i*brr;
                }
            }
            // --- CNOT ring: (0,1),(1,2),(2,3),(3,0) ---
            const int cs[4] = {0,1,2,3}, ts[4] = {1,2,3,0};
            #pragma unroll
            for (int e = 0; e < 4; ++e) {
                const int cb = 3 - cs[e], tb = 3 - ts[e];
                float nr[16], ni[16];
                #pragma unroll
                for (int k = 0; k < 16; ++k) {
                    const int src = ((k >> cb) & 1) ? (k ^ (1 << tb)) : k;
                    nr[k] = ur[src]; ni[k] = ui[src];
                }
                #pragma unroll
                for (int k = 0; k < 16; ++k) { ur[k] = nr[k]; ui[k] = ni[k]; }
            }
        }
        #pragma unroll
        for (int k = 0; k < 16; ++k) { Ur[k][col] = ur[k]; Ui[k][col] = ui[k]; }
    }
    __syncthreads();

    // Each of the 256 threads computes one (i,j) entry, all 4 observables.
    // M_q[i][j] = sum_k z_q(k) * (Ur[k][i]Ur[k][j] + Ui[k][i]Ui[k][j])
    // Off-diagonals doubled (main kernel only walks j >= i).
    const int i = tid >> 4, j = tid & 15;
    float m0 = 0.f, m1 = 0.f, m2 = 0.f, m3 = 0.f;
    #pragma unroll
    for (int k = 0; k < 16; ++k) {
        const float dot = Ur[k][i]*Ur[k][j] + Ui[k][i]*Ui[k][j];
        m0 += ((k >> 3) & 1) ? -dot : dot;
        m1 += ((k >> 2) & 1) ? -dot : dot;
        m2 += ((k >> 1) & 1) ? -dot : dot;
        m3 += ( k       & 1) ? -dot : dot;
    }
    const float sc = (i == j) ? 1.f : 2.f;
    float4 o; o.x = m0*sc; o.y = m1*sc; o.z = m2*sc; o.w = m3*sc;
    reinterpret_cast<float4*>(M)[i*16 + j] = o;
}

__global__ __launch_bounds__(256) void qc_main(const float4* __restrict__ x4,
                                               const float4* __restrict__ Mg,
                                               float4* __restrict__ out4)
{
    const int b = blockIdx.x * 256 + threadIdx.x;
    const float4* row = x4 + ((size_t)b << 4);

    // angle sums (x row is 64 floats = 16 float4; lanes of float4 = qubits)
    float a0 = 0.f, a1 = 0.f, a2 = 0.f, a3 = 0.f;
    #pragma unroll
    for (int j = 0; j < 16; ++j) {
        const float4 v = row[j];
        a0 += v.x; a1 += v.y; a2 += v.z; a3 += v.w;
    }

    // fast hw sin/cos (args |a|/2 ~ few sigma of N(0,16); well within range)
    float c0,s0,c1,s1,c2,s2,c3,s3;
    __sincosf(0.5f*a0, &s0, &c0);
    __sincosf(0.5f*a1, &s1, &c1);
    __sincosf(0.5f*a2, &s2, &c2);
    __sincosf(0.5f*a3, &s3, &c3);

    // psi[k], k = b0*8 + b1*4 + b2*2 + b3
    float p23[4] = { c2*c3, c2*s3, s2*c3, s2*s3 };
    float p123[8];
    #pragma unroll
    for (int t = 0; t < 4; ++t) { p123[t] = c1*p23[t]; p123[4+t] = s1*p23[t]; }
    float psi[16];
    #pragma unroll
    for (int u = 0; u < 8; ++u) { psi[u] = c0*p123[u]; psi[8+u] = s0*p123[u]; }

    // quadratic forms, upper triangle (off-diag pre-doubled in M).
    // Mg addresses are compile-time offsets off a uniform kernel arg ->
    // compiler emits s_load_dwordx4; SGPR operand feeds v_fma directly.
    float ax = 0.f, ay = 0.f, az = 0.f, aw = 0.f;
    #pragma unroll
    for (int i = 0; i < 16; ++i) {
        #pragma unroll
        for (int j = i; j < 16; ++j) {
            const float pp = psi[i] * psi[j];
            const float4 m = Mg[i*16 + j];   // wave-uniform -> scalar load
            ax = fmaf(pp, m.x, ax);
            ay = fmaf(pp, m.y, ay);
            az = fmaf(pp, m.z, az);
            aw = fmaf(pp, m.w, aw);
        }
    }
    float4 r; r.x = ax; r.y = ay; r.z = az; r.w = aw;
    out4[b] = r;
}

extern "C" void kernel_launch(void* const* d_in, const int* in_sizes, int n_in,
                              void* d_out, int out_size, void* d_ws, size_t ws_size,
                              hipStream_t stream)
{
    const float* x      = (const float*)d_in[0];
    const float* params = (const float*)d_in[1];
    float*       out    = (float*)d_out;
    float*       M      = (float*)d_ws;   // 1024 floats = 4KB

    qc_setup<<<1, 256, 0, stream>>>(params, M);

    const int batch = in_sizes[0] / 64;            // 131072
    qc_main<<<batch / 256, 256, 0, stream>>>(
        (const float4*)x, (const float4*)M, (float4*)out);
}